// Round 2
// 370.470 us; speedup vs baseline: 1.3456x; 1.3456x over previous
//
#include <hip/hip_runtime.h>

// VectorQuantizer: x (4,256,16,32,32) f32, weight (1024,256) f32.
// out[n*256+c] = weight[argmin_k d_np(n,k)][c], n in BTHW token order.
//
// Contract (R3, passed absmax 0): replicate numpy fp32 bit-for-bit:
//   sx/sw = np pairwise sumsq; m = sgemm sequential fma chain ascending c;
//   d = fl(fl(sx+sw) - 2m); argmin first-index.
// R4/R5 (passed): bf16-MFMA 3-product screen (err ~5e-5 << MARGIN=4e-4)
//   + exact resolve of near-ties.
// R6: screen v2 — old screen was latency-bound (172 VGPR -> 2 waves/SIMD;
//   every MFMA operand a 16-cache-line global gather; MfmaUtil 14.5%).
//   New structure: A (32 tokens/wave, full K, hi+lo) in 128 VGPRs loaded
//   once; W re-packed into MFMA-fragment-linear order (vq_wfrag, replaces
//   vq_split_w) so B staging is a linear copy and LDS reads are
//   lane-contiguous (bank-capacity optimal, no swizzle); B tile (16 codes,
//   16 KB) double-buffered in LDS, issue-early/write-late staging, one
//   barrier per kt. Per-(token,code) MFMA chain order and top-2/MARGIN
//   logic bitwise-identical to R5 screen. Also: vq_split_x stores
//   vectorized to bf16x8.
// R7: identical to R6 — previous round was an infra failure (container
//   never ran; no pytest/profile output). Re-running the experiment.

typedef __attribute__((ext_vector_type(8))) short bf16x8;
typedef __attribute__((ext_vector_type(4))) float f32x4;

#define MARGIN 4e-4f

__device__ __forceinline__ unsigned short bf16_rne(float f) {
    unsigned int u = __float_as_uint(f);
    unsigned int r = u + 0x7fffu + ((u >> 16) & 1u);
    return (unsigned short)(r >> 16);
}
__device__ __forceinline__ float bf16_to_f(unsigned short h) {
    return __uint_as_float(((unsigned int)h) << 16);
}

// ---- numpy pairwise sum of squares, n=256, contract OFF ----
__device__ __forceinline__ float np_sumsq_256(const float* __restrict__ p,
                                              long stride) {
#pragma clang fp contract(off)
    float half[2];
    #pragma unroll
    for (int h = 0; h < 2; ++h) {
        const float* q = p + (long)h * 128 * stride;
        float r[8];
        #pragma unroll
        for (int j = 0; j < 8; ++j) { float v = q[(long)j * stride]; r[j] = v * v; }
        for (int i = 8; i < 128; i += 8) {
            #pragma unroll
            for (int j = 0; j < 8; ++j) {
                float v = q[(long)(i + j) * stride];
                r[j] = r[j] + v * v;
            }
        }
        half[h] = ((r[0] + r[1]) + (r[2] + r[3])) + ((r[4] + r[5]) + (r[6] + r[7]));
    }
    return half[0] + half[1];
}

__global__ __launch_bounds__(256) void vq_sxq(const float* __restrict__ x,
                                              float* __restrict__ sxq) {
    const int n = blockIdx.x * 256 + threadIdx.x;
    const int b = n >> 14, thw = n & 16383;
    sxq[n] = np_sumsq_256(x + (long)b * 4194304 + thw, 16384);
}

__global__ __launch_bounds__(256) void vq_swq(const float* __restrict__ w,
                                              float* __restrict__ swq) {
    const int k = blockIdx.x * 256 + threadIdx.x;
    swq[k] = np_sumsq_256(w + (long)k * 256, 1);
}

// ---- W transpose Wt[c][k] (used by resolve v2 and the R3 fallback) ----
__global__ __launch_bounds__(64) void vq_wt(const float* __restrict__ w,
                                            float* __restrict__ wt) {
    const int k = blockIdx.x;
    const int lane = threadIdx.x;
    const float4 v = reinterpret_cast<const float4*>(w + (size_t)k * 256)[lane];
    wt[(size_t)(4 * lane + 0) * 1024 + k] = v.x;
    wt[(size_t)(4 * lane + 1) * 1024 + k] = v.y;
    wt[(size_t)(4 * lane + 2) * 1024 + k] = v.z;
    wt[(size_t)(4 * lane + 3) * 1024 + k] = v.w;
}

// ---- pack W into MFMA-fragment-linear bf16 hi/lo planes ----
// wf layout: tile kt (16 codes) = 8192 ushorts; within: cs*1024 +
// plane*512 + lane*8, where lane = lq*16+l15 and the 8 elems are
// w[kt*16+l15][cs*32+lq*8 .. +8] — exactly the B-fragment read order.
__global__ __launch_bounds__(256) void vq_wfrag(const float* __restrict__ w,
                                                unsigned short* __restrict__ wf) {
    const int T = blockIdx.x * 256 + threadIdx.x;     // [0, 32768)
    const int l15 = T & 15, lq = (T >> 4) & 3, cs = (T >> 6) & 7, kt = T >> 9;
    const float* src = w + (size_t)(kt * 16 + l15) * 256 + cs * 32 + lq * 8;
    bf16x8 vh, vl;
    #pragma unroll
    for (int e = 0; e < 8; ++e) {
        const float v = src[e];
        const unsigned short h = bf16_rne(v);
        vh[e] = (short)h;
        vl[e] = (short)bf16_rne(v - bf16_to_f(h));
    }
    unsigned short* dst = wf + (size_t)kt * 8192 + cs * 1024 + (lq * 128 + l15 * 8);
    *(bf16x8*)dst = vh;
    *(bf16x8*)(dst + 512) = vl;
}

// ---- split + transpose x into bf16 planes xh[n][c], xl[n][c] ----
// R6: float4 global loads, bf16x8 (16 B/lane) global stores.
__global__ __launch_bounds__(256) void vq_split_x(const float* __restrict__ x,
                                                  unsigned short* __restrict__ xh,
                                                  unsigned short* __restrict__ xl) {
    __shared__ float tile[64][68];   // stride 68: 16B-aligned float4 rows
    const int bid = blockIdx.x;
    const int b  = bid >> 10;
    const int ct = (bid >> 8) & 3;
    const int tt = bid & 255;
    const float* xb = x + (size_t)b * 4194304 + (size_t)(ct * 64) * 16384 + tt * 64;
    const int t4 = (threadIdx.x & 15) * 4;
    const int cg = threadIdx.x >> 4;   // 0..15
    #pragma unroll
    for (int i = 0; i < 4; ++i) {
        const int cc = i * 16 + cg;
        *(float4*)&tile[cc][t4] = *(const float4*)(xb + (size_t)cc * 16384 + t4);
    }
    __syncthreads();
    const int co = threadIdx.x & 7;    // group of 8 channels
    const int tg = threadIdx.x >> 3;   // 0..31
    #pragma unroll
    for (int i = 0; i < 2; ++i) {
        const int t = tg * 2 + i;
        bf16x8 vh, vl;
        #pragma unroll
        for (int ee = 0; ee < 8; ++ee) {
            const int e = (ee + co) & 7;   // rotate e by co: spreads LDS banks
            const float v = tile[co * 8 + e][t];
            const unsigned short h = bf16_rne(v);
            vh[e] = (short)h;
            vl[e] = (short)bf16_rne(v - bf16_to_f(h));
        }
        const size_t n = (size_t)b * 16384 + (size_t)tt * 64 + t;
        *(bf16x8*)(xh + n * 256 + ct * 64 + co * 8) = vh;
        *(bf16x8*)(xl + n * 256 + ct * 64 + co * 8) = vl;
    }
}

// ---- screen v2: A-in-regs, fragment-linear B tiles double-buffered in LDS ----
// Block = 4 waves x 32 tokens = 128 tokens; all 1024 codes streamed as 64
// tiles of 16. Per (token,code) the acc chain (cs ascending; hh,lh,hl) is
// bitwise-identical to R5's screen.
__global__ __launch_bounds__(256, 2) void vq_screen2(const unsigned short* __restrict__ xh,
                                                     const unsigned short* __restrict__ xl,
                                                     const unsigned short* __restrict__ wf,
                                                     const float* __restrict__ swq,
                                                     int* __restrict__ winner,
                                                     int* __restrict__ flag,
                                                     int* __restrict__ count) {
    __shared__ __align__(16) unsigned short btile[2][8192];  // 2 x 16 KB
    __shared__ __align__(16) float sw_s[1024];

    const int tid  = threadIdx.x;
    const int wv   = tid >> 6;
    const int lane = tid & 63;
    const int l15  = lane & 15, lq = lane >> 4;
    const int n0   = blockIdx.x * 128;

    reinterpret_cast<float4*>(sw_s)[tid] = reinterpret_cast<const float4*>(swq)[tid];

    // A fragments: 32 tokens/wave (2 sub-tiles of 16), full K=256, hi+lo.
    bf16x8 ah0[8], al0[8], ah1[8], al1[8];
    {
        const size_t a0 = (size_t)(n0 + wv * 32 + l15) * 256 + lq * 8;
        const size_t a1 = a0 + 16 * 256;
        #pragma unroll
        for (int cs = 0; cs < 8; ++cs) {
            ah0[cs] = *(const bf16x8*)(xh + a0 + cs * 32);
            al0[cs] = *(const bf16x8*)(xl + a0 + cs * 32);
            ah1[cs] = *(const bf16x8*)(xh + a1 + cs * 32);
            al1[cs] = *(const bf16x8*)(xl + a1 + cs * 32);
        }
    }

    // prologue: stage tile kt=0 (linear copy, 4 KB per wave)
    {
        const unsigned short* src = wf + wv * 2048 + lane * 8;
        unsigned short* dst = &btile[0][wv * 2048 + lane * 8];
        #pragma unroll
        for (int j = 0; j < 4; ++j)
            *(bf16x8*)(dst + j * 512) = *(const bf16x8*)(src + j * 512);
    }
    __syncthreads();

    float m1[8], m2[8];
    int   i1[8];
    #pragma unroll
    for (int j = 0; j < 8; ++j) { m1[j] = 1e30f; m2[j] = 1e30f; i1[j] = 0; }

    for (int kt = 0; kt < 64; ++kt) {
        const int cur = kt & 1;

        // issue next tile's global loads early (write-late below)
        bf16x8 stg[4];
        if (kt < 63) {
            const unsigned short* src = wf + (size_t)(kt + 1) * 8192 + wv * 2048 + lane * 8;
            #pragma unroll
            for (int j = 0; j < 4; ++j) stg[j] = *(const bf16x8*)(src + j * 512);
        }

        f32x4 acc0 = (f32x4){0.f, 0.f, 0.f, 0.f};
        f32x4 acc1 = (f32x4){0.f, 0.f, 0.f, 0.f};
        const unsigned short* bp = &btile[cur][lane * 8];
        #pragma unroll
        for (int cs = 0; cs < 8; ++cs) {
            const bf16x8 bh = *(const bf16x8*)(bp + cs * 1024);
            const bf16x8 bl = *(const bf16x8*)(bp + cs * 1024 + 512);
            acc0 = __builtin_amdgcn_mfma_f32_16x16x32_bf16(ah0[cs], bh, acc0, 0, 0, 0);
            acc0 = __builtin_amdgcn_mfma_f32_16x16x32_bf16(al0[cs], bh, acc0, 0, 0, 0);
            acc0 = __builtin_amdgcn_mfma_f32_16x16x32_bf16(ah0[cs], bl, acc0, 0, 0, 0);
            acc1 = __builtin_amdgcn_mfma_f32_16x16x32_bf16(ah1[cs], bh, acc1, 0, 0, 0);
            acc1 = __builtin_amdgcn_mfma_f32_16x16x32_bf16(al1[cs], bh, acc1, 0, 0, 0);
            acc1 = __builtin_amdgcn_mfma_f32_16x16x32_bf16(ah1[cs], bl, acc1, 0, 0, 0);
        }

        const int k = kt * 16 + l15;      // C/D col = l15
        const float snk = sw_s[k];
        #pragma unroll
        for (int r = 0; r < 4; ++r) {
            const float d0 = fmaf(-2.f, acc0[r], snk);
            if (d0 < m1[r]) { m2[r] = m1[r]; m1[r] = d0; i1[r] = k; }
            else            m2[r] = fminf(m2[r], d0);
            const float d1 = fmaf(-2.f, acc1[r], snk);
            if (d1 < m1[4 + r]) { m2[4 + r] = m1[4 + r]; m1[4 + r] = d1; i1[4 + r] = k; }
            else                m2[4 + r] = fminf(m2[4 + r], d1);
        }

        // write-late: park next tile into the other buffer, then barrier
        if (kt < 63) {
            unsigned short* dst = &btile[cur ^ 1][wv * 2048 + lane * 8];
            #pragma unroll
            for (int j = 0; j < 4; ++j) *(bf16x8*)(dst + j * 512) = stg[j];
        }
        __syncthreads();
    }

    // reduce across the 16 l15 lanes (lane's codes are ≡ l15 mod 16)
    #pragma unroll
    for (int mm = 1; mm < 16; mm <<= 1) {
        #pragma unroll
        for (int j = 0; j < 8; ++j) {
            const float om1 = __shfl_xor(m1[j], mm);
            const int   oi1 = __shfl_xor(i1[j], mm);
            const float om2 = __shfl_xor(m2[j], mm);
            if (om1 < m1[j]) { m2[j] = fminf(m1[j], om2); m1[j] = om1; i1[j] = oi1; }
            else             { m2[j] = fminf(m2[j], om1); }
        }
    }
    if (l15 == 0) {
        #pragma unroll
        for (int mt = 0; mt < 2; ++mt)
            #pragma unroll
            for (int r = 0; r < 4; ++r) {
                const int j = mt * 4 + r;
                const int n = n0 + wv * 32 + mt * 16 + lq * 4 + r;
                if (m2[j] - m1[j] > MARGIN) {
                    winner[n] = i1[j];
                } else {
                    winner[n] = -1;
                    const int p = atomicAdd(count, 1);
                    flag[p] = n;
                }
            }
    }
}

// ---- resolve v2: np-exact rescore of flagged tokens, coalesced wt loads ----
__global__ __launch_bounds__(256) void vq_resolve2(const float* __restrict__ x,
                                                   const float* __restrict__ wt,
                                                   const float* __restrict__ sxq,
                                                   const float* __restrict__ swq,
                                                   const int* __restrict__ flag,
                                                   const int* __restrict__ count,
                                                   int* __restrict__ winner) {
    __shared__ float xsh[4][256];
    __shared__ int   toks[4];
    __shared__ float r_d[4][4];
    __shared__ int   r_k[4][4];

    const int cnt = *count;
    const int tid = threadIdx.x;
    const int groups = (cnt + 3) >> 2;

    for (int g = blockIdx.x; g < groups; g += gridDim.x) {
        if (tid < 4) toks[tid] = (4 * g + tid < cnt) ? flag[4 * g + tid] : -1;
        __syncthreads();
        #pragma unroll
        for (int i = 0; i < 4; i++) {
            const int n = toks[i];
            float v = 0.f;
            if (n >= 0) {
                const int b = n >> 14, thw = n & 16383;
                v = x[(size_t)b * 4194304 + (size_t)tid * 16384 + thw];
            }
            xsh[i][tid] = v;
        }
        __syncthreads();

        float acc[4][4];   // [q][token]
        #pragma unroll
        for (int q = 0; q < 4; q++)
            #pragma unroll
            for (int i = 0; i < 4; i++) acc[q][i] = 0.f;

        const float* wp = wt + tid;
        #pragma unroll 4
        for (int c = 0; c < 256; c++) {
            const float w0 = wp[(size_t)c * 1024 + 0];
            const float w1 = wp[(size_t)c * 1024 + 256];
            const float w2 = wp[(size_t)c * 1024 + 512];
            const float w3 = wp[(size_t)c * 1024 + 768];
            #pragma unroll
            for (int i = 0; i < 4; i++) {
                const float xc = xsh[i][c];
                acc[0][i] = fmaf(xc, w0, acc[0][i]);
                acc[1][i] = fmaf(xc, w1, acc[1][i]);
                acc[2][i] = fmaf(xc, w2, acc[2][i]);
                acc[3][i] = fmaf(xc, w3, acc[3][i]);
            }
        }

        // np distances + lexicographic (d,k) argmin per token
        const float swk[4] = {swq[tid], swq[tid + 256], swq[tid + 512], swq[tid + 768]};
        #pragma unroll
        for (int i = 0; i < 4; i++) {
            const int n = toks[i];
            float bd = 1e30f;
            int   bk = 0x7fffffff;
            if (n >= 0) {
                const float sx = sxq[n];
                #pragma unroll
                for (int q = 0; q < 4; q++) {
                    const int k = tid + 256 * q;
                    const float s1 = sx + swk[q];
                    const float d  = fmaf(-2.f, acc[q][i], s1);
                    if (d < bd || (d == bd && k < bk)) { bd = d; bk = k; }
                }
            }
            #pragma unroll
            for (int mm = 1; mm < 64; mm <<= 1) {
                const float od = __shfl_xor(bd, mm);
                const int   ok = __shfl_xor(bk, mm);
                if (od < bd || (od == bd && ok < bk)) { bd = od; bk = ok; }
            }
            if ((tid & 63) == 0) { r_d[tid >> 6][i] = bd; r_k[tid >> 6][i] = bk; }
        }
        __syncthreads();
        if (tid < 4) {
            const int n = toks[tid];
            if (n >= 0) {
                float bd = r_d[0][tid]; int bk = r_k[0][tid];
                #pragma unroll
                for (int wv = 1; wv < 4; wv++) {
                    const float od = r_d[wv][tid];
                    const int   ok = r_k[wv][tid];
                    if (od < bd || (od == bd && ok < bk)) { bd = od; bk = ok; }
                }
                winner[n] = bk;
            }
        }
        __syncthreads();
    }
}

// ---- gather ----
__global__ __launch_bounds__(256) void vq_gather(const float* __restrict__ w,
                                                 const int* __restrict__ winner,
                                                 float* __restrict__ out) {
    const size_t idx = (size_t)blockIdx.x * 256 + threadIdx.x;
    const int n = (int)(idx >> 6);
    const int c4 = (int)(idx & 63);
    reinterpret_cast<float4*>(out)[idx] =
        reinterpret_cast<const float4*>(w + (size_t)winner[n] * 256)[c4];
}

// ================= R3 fallback (proven-correct) =================
#define TPB 32
__global__ __launch_bounds__(256) void vq_main(const float* __restrict__ x,
                                               const float* __restrict__ sxq,
                                               const float* __restrict__ swq,
                                               const float* __restrict__ wt,
                                               const float* __restrict__ weight,
                                               float* __restrict__ out) {
    __shared__ __align__(16) float xs[256 * TPB];
    __shared__ float wn[1024];
    __shared__ float sxs[TPB];
    __shared__ float red_s[4][TPB];
    __shared__ int   red_i[4][TPB];
    __shared__ int   fidx[TPB];

    const int tid = threadIdx.x;
    const int n0 = blockIdx.x * TPB;
    const int b = n0 >> 14, thw = n0 & 16383;
    const float* xb = x + (size_t)b * 4194304 + thw;

    for (int i = tid; i < 256 * TPB; i += 256) {
        int t = i & (TPB - 1);
        int c = i >> 5;
        xs[c * TPB + t] = xb[(size_t)c * 16384 + t];
    }
    for (int i = tid; i < 1024; i += 256) wn[i] = swq[i];
    if (tid < TPB) sxs[tid] = sxq[n0 + tid];
    __syncthreads();

    const int lane = tid & 63, wv = tid >> 6;
    const int tg = lane & 7, cg = lane >> 3;
    float sxr[4];
    #pragma unroll
    for (int j = 0; j < 4; j++) sxr[j] = sxs[4 * tg + j];
    float bestS[4]; int bestI[4];
    #pragma unroll
    for (int j = 0; j < 4; j++) { bestS[j] = 1e30f; bestI[j] = 0x7fffffff; }

    for (int kb = 0; kb < 1024; kb += 256) {
        const int kbase = kb + 64 * wv + 8 * cg;
        float acc[4][8];
        #pragma unroll
        for (int j = 0; j < 4; j++)
            #pragma unroll
            for (int q = 0; q < 8; q++) acc[j][q] = 0.f;
        const float* wtp = wt + kbase;
        #pragma unroll 4
        for (int c = 0; c < 256; c++) {
            const float4 xv = *reinterpret_cast<const float4*>(&xs[c * TPB + 4 * tg]);
            const float4 w0 = *reinterpret_cast<const float4*>(wtp + (size_t)c * 1024);
            const float4 w1 = *reinterpret_cast<const float4*>(wtp + (size_t)c * 1024 + 4);
            const float xr[4] = {xv.x, xv.y, xv.z, xv.w};
            const float wr[8] = {w0.x, w0.y, w0.z, w0.w, w1.x, w1.y, w1.z, w1.w};
            #pragma unroll
            for (int j = 0; j < 4; j++)
                #pragma unroll
                for (int q = 0; q < 8; q++)
                    acc[j][q] = fmaf(xr[j], wr[q], acc[j][q]);
        }
        #pragma unroll
        for (int q = 0; q < 8; q++) {
            const int k = kbase + q;
            const float wnk = wn[k];
            #pragma unroll
            for (int j = 0; j < 4; j++) {
                const float s1 = sxr[j] + wnk;
                const float d = fmaf(-2.f, acc[j][q], s1);
                if (d < bestS[j]) { bestS[j] = d; bestI[j] = k; }
            }
        }
    }
    #pragma unroll
    for (int m = 8; m < 64; m <<= 1) {
        #pragma unroll
        for (int j = 0; j < 4; j++) {
            const float os = __shfl_xor(bestS[j], m);
            const int   oi = __shfl_xor(bestI[j], m);
            if (os < bestS[j] || (os == bestS[j] && oi < bestI[j])) {
                bestS[j] = os; bestI[j] = oi;
            }
        }
    }
    if (cg == 0) {
        #pragma unroll
        for (int j = 0; j < 4; j++) {
            red_s[wv][4 * tg + j] = bestS[j];
            red_i[wv][4 * tg + j] = bestI[j];
        }
    }
    __syncthreads();
    if (tid < TPB) {
        float bs = red_s[0][tid]; int bi = red_i[0][tid];
        #pragma unroll
        for (int w2 = 1; w2 < 4; w2++) {
            const float s2 = red_s[w2][tid];
            const int   i2 = red_i[w2][tid];
            if (s2 < bs || (s2 == bs && i2 < bi)) { bs = s2; bi = i2; }
        }
        fidx[tid] = bi;
    }
    __syncthreads();
    for (int i = tid; i < TPB * 256; i += 256) {
        const int t = i >> 8, c = i & 255;
        out[(size_t)(n0 + t) * 256 + c] = weight[(size_t)fidx[t] * 256 + c];
    }
}

// ================= launch =================
extern "C" void kernel_launch(void* const* d_in, const int* in_sizes, int n_in,
                              void* d_out, int out_size, void* d_ws, size_t ws_size,
                              hipStream_t stream) {
    const float* x = (const float*)d_in[0];
    const float* w = (const float*)d_in[1];
    float* out = (float*)d_out;

    char* p = (char*)d_ws;
    int*   count  = (int*)p;                         p += 256;
    int*   winner = (int*)p;                         p += 65536 * 4;
    int*   flag   = (int*)p;                         p += 65536 * 4;
    float* sxq    = (float*)p;                       p += 65536 * 4;
    float* swq    = (float*)p;                       p += 1024 * 4;
    float* wt     = (float*)p;                       p += 262144 * 4;
    unsigned short* wf = (unsigned short*)p;         p += 524288 * 2;
    unsigned short* xh = (unsigned short*)p;         p += 16777216 * 2;
    unsigned short* xl = (unsigned short*)p;         p += 16777216 * 2;
    const size_t need_fast = (size_t)(p - (char*)d_ws);

    if (ws_size >= need_fast) {
        hipMemsetAsync(count, 0, 4, stream);
        vq_sxq<<<256, 256, 0, stream>>>(x, sxq);
        vq_swq<<<4, 256, 0, stream>>>(w, swq);
        vq_wt<<<1024, 64, 0, stream>>>(w, wt);
        vq_wfrag<<<128, 256, 0, stream>>>(w, wf);
        vq_split_x<<<4096, 256, 0, stream>>>(x, xh, xl);
        vq_screen2<<<512, 256, 0, stream>>>(xh, xl, wf, swq, winner, flag, count);
        vq_resolve2<<<1024, 256, 0, stream>>>(x, wt, sxq, swq, flag, count, winner);
        vq_gather<<<16384, 256, 0, stream>>>(w, winner, out);
    } else {
        // proven R3 fallback (needs ~1.3 MB)
        float* sxq2 = (float*)d_ws;
        float* swq2 = sxq2 + 65536;
        float* wt2  = swq2 + 1024;
        vq_sxq<<<256, 256, 0, stream>>>(x, sxq2);
        vq_swq<<<4, 256, 0, stream>>>(w, swq2);
        vq_wt<<<1024, 64, 0, stream>>>(w, wt2);
        vq_main<<<65536 / TPB, 256, 0, stream>>>(x, sxq2, swq2, wt2, w, out);
    }
}